// Round 5
// baseline (599.031 us; speedup 1.0000x reference)
//
#include <hip/hip_runtime.h>
#include <hip/hip_bf16.h>

#define NGROUPS 131072
#define H 128
#define SG 3            // group size
#define NHEADS 4
#define HD 32
#define GB 16           // groups per block
#define MR 48           // rows per block (= GB*SG)
#define NT 512          // threads per block (8 waves)
#define BP 136          // bf16 LDS row stride (elements); keeps b128 16B-aligned
#define NLAYERS 2

typedef unsigned short u16;
typedef unsigned int u32;
typedef __bf16 bf16x8 __attribute__((ext_vector_type(8)));
typedef float floatx4 __attribute__((ext_vector_type(4)));

__device__ __forceinline__ float bf2f_lo(u32 u) {
  union { u32 i; float f; } c; c.i = u << 16; return c.f;
}
__device__ __forceinline__ float bf2f_hi(u32 u) {
  union { u32 i; float f; } c; c.i = u & 0xffff0000u; return c.f;
}
// packed f32x2 -> bf16x2 (v_cvt_pk_bf16_f32 on gfx950), RNE
__device__ __forceinline__ u32 f2bf2(float a, float b) {
  __hip_bfloat162 h = __float22bfloat162_rn(make_float2(a, b));
  union { __hip_bfloat162 h; u32 u; } c; c.h = h; return c.u;
}
__device__ __forceinline__ u16 f2bf(float f) {
  union { float f; u32 i; } c; c.f = f;
  u32 x = c.i; x += 0x7fffu + ((x >> 16) & 1u);
  return (u16)(x >> 16);
}

// ---- weight convert + transpose: wt[slot][n][k] = W[slot][k][n] as bf16 ----
__global__ void wconv_kernel(const float* __restrict__ Ws, const float* __restrict__ Wq,
                             const float* __restrict__ Wk, const float* __restrict__ Wv,
                             const float* __restrict__ Wo, u16* __restrict__ wt) {
  int idx = blockIdx.x * 256 + threadIdx.x;      // grid sized exactly (9*16384/256)
  int slot = idx >> 14;
  int rem = idx & 16383;
  int n = rem >> 7, k = rem & 127;
  const float* src;
  if (slot == 0) src = Ws;
  else {
    int l = (slot - 1) >> 2, t = (slot - 1) & 3;
    const float* base = (t == 0) ? Wq : (t == 1) ? Wk : (t == 2) ? Wv : Wo;
    src = base + l * (H * H);
  }
  wt[idx] = f2bf(src[k * H + n]);
}

// NP projections sharing one LDS B-operand; B-frags streamed per k-slice.
// D[outcol=(lane>>4)*4+r][generow=lane&15]: thread owns 1 gene-row x 4 cols per nt.
template <int NP>
__device__ __forceinline__ void multi_proj(const u16* __restrict__ lds,
                                           const u16* __restrict__ w0,
                                           floatx4 acc[NP][3], int m0, int qi, int wrow) {
#pragma unroll
  for (int p = 0; p < NP; p++)
#pragma unroll
    for (int nt = 0; nt < 3; nt++)
      acc[p][nt] = (floatx4){0.f, 0.f, 0.f, 0.f};
#pragma unroll
  for (int kk = 0; kk < 4; kk++) {
    bf16x8 b[3];
#pragma unroll
    for (int nt = 0; nt < 3; nt++)
      b[nt] = *reinterpret_cast<const bf16x8*>(lds + (nt * 16 + m0) * BP + kk * 32 + qi * 8);
#pragma unroll
    for (int p = 0; p < NP; p++) {
      bf16x8 a = *reinterpret_cast<const bf16x8*>(w0 + (size_t)p * H * H + wrow * H + kk * 32 + qi * 8);
#pragma unroll
      for (int nt = 0; nt < 3; nt++)
        acc[p][nt] = __builtin_amdgcn_mfma_f32_16x16x32_bf16(a, b[nt], acc[p][nt], 0, 0, 0);
    }
  }
}

// store acc+bias as packed bf16, 4 consecutive cols per row -> one b64 write per nt
__device__ __forceinline__ void store_proj(u16* __restrict__ buf, const floatx4 acc[3],
                                           float4 b4, int m0, int colb) {
#pragma unroll
  for (int nt = 0; nt < 3; nt++) {
    uint2 pp;
    pp.x = f2bf2(acc[nt][0] + b4.x, acc[nt][1] + b4.y);
    pp.y = f2bf2(acc[nt][2] + b4.z, acc[nt][3] + b4.w);
    *reinterpret_cast<uint2*>(buf + (nt * 16 + m0) * BP + colb) = pp;
  }
}

__global__ void __launch_bounds__(NT)
__attribute__((amdgpu_waves_per_eu(6)))   // target 6 waves/SIMD -> 3 blocks/CU; live unified ~76 regs
dango_kernel(const float* __restrict__ x, const u16* __restrict__ wt,
             const float* __restrict__ bs, const float* __restrict__ bq,
             const float* __restrict__ bk, const float* __restrict__ bv,
             const float* __restrict__ bo, const float* __restrict__ beta,
             const float* __restrict__ Wp, const float* __restrict__ bp,
             float* __restrict__ out)
{
  // ~41 KB LDS -> 3 blocks/CU (LDS-wise); VGPR budget must also allow 6 waves/SIMD
  __shared__ __align__(16) u16 xbf[MR][BP];   // residual (bf16 IS the residual now)
  __shared__ __align__(16) u16 qbuf[MR][BP];  // Q, then V
  __shared__ __align__(16) u16 kbuf[MR][BP];  // K, then attention-out
  __shared__ __align__(16) float ovl[MR * 9]; // overlay: attnw (384 f) / rowsc (432 f)
#define ATTNW(g, h, i, p) ovl[((((g) * NHEADS + (h)) * SG + (i)) << 1) + (p)]
#define ROWSC(r, w) ovl[(r) * 9 + (w)]

  const int tid = threadIdx.x;
  const int lane = tid & 63;
  const int wave = tid >> 6;          // 0..7: owns outcols wave*16..wave*16+15
  const int m0 = lane & 15;           // gene-row index within nt-tile
  const int qi = lane >> 4;           // 0..3: 4-col window within wave's 16
  const int colb = wave * 16 + qi * 4;
  const int wrow = wave * 16 + m0;    // weight row (outcol) this lane loads
  const int row0 = blockIdx.x * MR;

  u32 statpk[3][2];                   // static embedding, packed bf16
  float dynf[3][4];                   // final-layer dyn (valid after last O-proj)

  // ---- init: x -> xbf (bf16 residual) ----
#pragma unroll
  for (int nt = 0; nt < 3; nt++) {
    int row = nt * 16 + m0;
    float4 v = *reinterpret_cast<const float4*>(x + (size_t)(row0 + row) * H + colb);
    uint2 pp; pp.x = f2bf2(v.x, v.y); pp.y = f2bf2(v.z, v.w);
    *reinterpret_cast<uint2*>(&xbf[row][colb]) = pp;
  }
  __syncthreads();

  // ---- phase A: static+Q (NP=2, slots 0,1), then K (slot 2); accum live <= 24 ----
  {
    floatx4 acc2[2][3];
    multi_proj<2>(&xbf[0][0], wt, acc2, m0, qi, wrow);
    {
      float4 b4 = *reinterpret_cast<const float4*>(bs + colb);
#pragma unroll
      for (int nt = 0; nt < 3; nt++) {
        statpk[nt][0] = f2bf2(fmaxf(acc2[0][nt][0] + b4.x, 0.f), fmaxf(acc2[0][nt][1] + b4.y, 0.f));
        statpk[nt][1] = f2bf2(fmaxf(acc2[0][nt][2] + b4.z, 0.f), fmaxf(acc2[0][nt][3] + b4.w, 0.f));
      }
    }
    store_proj(&qbuf[0][0], acc2[1], *reinterpret_cast<const float4*>(bq + colb), m0, colb);
    floatx4 acc1[1][3];
    multi_proj<1>(&xbf[0][0], wt + (size_t)2 * H * H, acc1, m0, qi, wrow);
    store_proj(&kbuf[0][0], acc1[0], *reinterpret_cast<const float4*>(bk + colb), m0, colb);
  }
  __syncthreads();

  for (int l = 0; l < NLAYERS; l++) {
    // ---- scores + 2-way softmax (self excluded): qbuf(Q), kbuf(K) -> attnw ----
    if (tid < GB * NHEADS * SG) {
      int g = tid / (NHEADS * SG);
      int rem = tid % (NHEADS * SG);
      int h = rem / SG;
      int i = rem % SG;
      int j0 = (i == 0) ? 1 : 0;
      int j1 = (i == 2) ? 1 : 2;
      const uint4* qp  = reinterpret_cast<const uint4*>(&qbuf[g * 3 + i][h * HD]);
      const uint4* k0p = reinterpret_cast<const uint4*>(&kbuf[g * 3 + j0][h * HD]);
      const uint4* k1p = reinterpret_cast<const uint4*>(&kbuf[g * 3 + j1][h * HD]);
      float s0 = 0.f, s1 = 0.f;
#pragma unroll
      for (int c = 0; c < 4; c++) {
        uint4 qu = qp[c], u0 = k0p[c], u1 = k1p[c];
        u32 qs[4] = {qu.x, qu.y, qu.z, qu.w};
        u32 a0[4] = {u0.x, u0.y, u0.z, u0.w};
        u32 a1[4] = {u1.x, u1.y, u1.z, u1.w};
#pragma unroll
        for (int e = 0; e < 4; e++) {
          float ql = bf2f_lo(qs[e]), qh = bf2f_hi(qs[e]);
          s0 += ql * bf2f_lo(a0[e]) + qh * bf2f_hi(a0[e]);
          s1 += ql * bf2f_lo(a1[e]) + qh * bf2f_hi(a1[e]);
        }
      }
      s0 *= 0.17677669529663687f;   // 1/sqrt(32)
      s1 *= 0.17677669529663687f;
      float mx = fmaxf(s0, s1);
      float e0 = __expf(s0 - mx), e1 = __expf(s1 - mx);
      float inv = 1.f / (e0 + e1);
      ATTNW(g, h, i, 0) = e0 * inv;
      ATTNW(g, h, i, 1) = e1 * inv;
    }
    __syncthreads();   // Q,K reads done; attnw visible

    // ---- V projection (slot 1+4l+2) -> qbuf (Q dead) ----
    {
      floatx4 acc1[1][3];
      multi_proj<1>(&xbf[0][0], wt + (size_t)(1 + l * 4 + 2) * H * H, acc1, m0, qi, wrow);
      store_proj(&qbuf[0][0], acc1[0], *reinterpret_cast<const float4*>(bv + l * H + colb), m0, colb);
    }
    __syncthreads();   // V visible; also fences xbf reads before O-proj RMW

    // ---- attention-out = attn @ V : qbuf(V) -> kbuf (K dead) ----
    for (int ch = tid; ch < MR * 16; ch += NT) {
      int r = ch >> 4, c0 = (ch & 15) << 3;
      int g = r / 3, i = r - g * 3, h = c0 >> 5;
      int j0 = (i == 0) ? 1 : 0;
      int j1 = (i == 2) ? 1 : 2;
      float a0 = ATTNW(g, h, i, 0), a1 = ATTNW(g, h, i, 1);
      uint4 v0 = *reinterpret_cast<const uint4*>(&qbuf[g * 3 + j0][c0]);
      uint4 v1 = *reinterpret_cast<const uint4*>(&qbuf[g * 3 + j1][c0]);
      u32 w0[4] = {v0.x, v0.y, v0.z, v0.w};
      u32 w1[4] = {v1.x, v1.y, v1.z, v1.w};
      u32 oo[4];
#pragma unroll
      for (int e = 0; e < 4; e++) {
        float lo = a0 * bf2f_lo(w0[e]) + a1 * bf2f_lo(w1[e]);
        float hi = a0 * bf2f_hi(w0[e]) + a1 * bf2f_hi(w1[e]);
        oo[e] = f2bf2(lo, hi);
      }
      uint4 o; o.x = oo[0]; o.y = oo[1]; o.z = oo[2]; o.w = oo[3];
      *reinterpret_cast<uint4*>(&kbuf[r][c0]) = o;
    }
    __syncthreads();   // attn-out visible

    // ---- O-projection (slot 1+4l+3) + ReZero RMW on xbf (own cells) ----
    {
      floatx4 acc1[1][3];
      multi_proj<1>(&kbuf[0][0], wt + (size_t)(1 + l * 4 + 3) * H * H, acc1, m0, qi, wrow);
      float4 b4 = *reinterpret_cast<const float4*>(bo + l * H + colb);
      const float betal = beta[l];
#pragma unroll
      for (int nt = 0; nt < 3; nt++) {
        int row = nt * 16 + m0;
        uint2 pp = *reinterpret_cast<const uint2*>(&xbf[row][colb]);
        float r0 = bf2f_lo(pp.x) + betal * (acc1[0][nt][0] + b4.x);
        float r1 = bf2f_hi(pp.x) + betal * (acc1[0][nt][1] + b4.y);
        float r2 = bf2f_lo(pp.y) + betal * (acc1[0][nt][2] + b4.z);
        float r3 = bf2f_hi(pp.y) + betal * (acc1[0][nt][3] + b4.w);
        if (l + 1 < NLAYERS) {
          uint2 np; np.x = f2bf2(r0, r1); np.y = f2bf2(r2, r3);
          *reinterpret_cast<uint2*>(&xbf[row][colb]) = np;
        } else {
          dynf[nt][0] = r0; dynf[nt][1] = r1; dynf[nt][2] = r2; dynf[nt][3] = r3;
        }
      }
    }

    if (l + 1 < NLAYERS) {
      __syncthreads();   // new residual visible
      // ---- Q,K of layer l+1 (NP=2, slots consecutive) ----
      floatx4 acc2[2][3];
      multi_proj<2>(&xbf[0][0], wt + (size_t)(1 + (l + 1) * 4) * H * H, acc2, m0, qi, wrow);
      store_proj(&qbuf[0][0], acc2[0], *reinterpret_cast<const float4*>(bq + (l + 1) * H + colb), m0, colb);
      store_proj(&kbuf[0][0], acc2[1], *reinterpret_cast<const float4*>(bk + (l + 1) * H + colb), m0, colb);
      __syncthreads();
    }
  }

  // ---- readout: gene score = sum_c (dyn-stat)^2 * Wp[c]; group mean ----
  float4 wp4 = *reinterpret_cast<const float4*>(Wp + colb);
  float rsum[3];
#pragma unroll
  for (int nt = 0; nt < 3; nt++) {
    float d0 = dynf[nt][0] - bf2f_lo(statpk[nt][0]);
    float d1 = dynf[nt][1] - bf2f_hi(statpk[nt][0]);
    float d2 = dynf[nt][2] - bf2f_lo(statpk[nt][1]);
    float d3 = dynf[nt][3] - bf2f_hi(statpk[nt][1]);
    rsum[nt] = d0 * d0 * wp4.x + d1 * d1 * wp4.y + d2 * d2 * wp4.z + d3 * d3 * wp4.w;
  }
  // reduce over qi (lane bits 4,5): each row's 16 cols within this wave
#pragma unroll
  for (int nt = 0; nt < 3; nt++) {
    rsum[nt] += __shfl_xor(rsum[nt], 16, 64);
    rsum[nt] += __shfl_xor(rsum[nt], 32, 64);
  }
  if (qi == 0) {
#pragma unroll
    for (int nt = 0; nt < 3; nt++)
      ROWSC(nt * 16 + m0, wave) = rsum[nt];
  }
  __syncthreads();
  if (tid < GB) {
    float s = 0.f;
#pragma unroll
    for (int i = 0; i < SG; i++) {
      int row = tid * 3 + i;
#pragma unroll
      for (int w = 0; w < 8; w++) s += ROWSC(row, w);
    }
    out[blockIdx.x * GB + tid] = s * (1.f / 3.f) + bp[0];
  }
}

extern "C" void kernel_launch(void* const* d_in, const int* in_sizes, int n_in,
                              void* d_out, int out_size, void* d_ws, size_t ws_size,
                              hipStream_t stream) {
  const float* x    = (const float*)d_in[0];
  // d_in[1] = batch ids: deterministic repeat(arange(G),3) -> not needed
  const float* Ws   = (const float*)d_in[2];
  const float* bs   = (const float*)d_in[3];
  const float* Wq   = (const float*)d_in[4];
  const float* bq   = (const float*)d_in[5];
  const float* Wk   = (const float*)d_in[6];
  const float* bk   = (const float*)d_in[7];
  const float* Wv   = (const float*)d_in[8];
  const float* bv   = (const float*)d_in[9];
  const float* Wo   = (const float*)d_in[10];
  const float* bo   = (const float*)d_in[11];
  const float* beta = (const float*)d_in[12];
  const float* Wp   = (const float*)d_in[13];
  const float* bp   = (const float*)d_in[14];
  float* out = (float*)d_out;
  u16* wt = (u16*)d_ws;   // 9 * 128*128 bf16 = 294,912 B

  // ws is re-poisoned before every launch -> convert every call
  wconv_kernel<<<576, 256, 0, stream>>>(Ws, Wq, Wk, Wv, Wo, wt);
  dango_kernel<<<NGROUPS / GB, NT, 0, stream>>>(x, wt, bs, bq, bk, bv, bo, beta, Wp, bp, out);
}

// Round 6
// 583.951 us; speedup vs baseline: 1.0258x; 1.0258x over previous
//
#include <hip/hip_runtime.h>
#include <hip/hip_bf16.h>

#define NGROUPS 131072
#define H 128
#define SG 3            // group size
#define NHEADS 4
#define HD 32
#define GB 16           // groups per block
#define MR 48           // rows per block (= GB*SG)
#define NT 512          // threads per block (8 waves)
#define BP 136          // bf16 LDS row stride (elements); keeps b128 16B-aligned
#define NLAYERS 2

typedef unsigned short u16;
typedef unsigned int u32;
typedef __bf16 bf16x8 __attribute__((ext_vector_type(8)));
typedef float floatx4 __attribute__((ext_vector_type(4)));

__device__ __forceinline__ float bf2f_lo(u32 u) {
  union { u32 i; float f; } c; c.i = u << 16; return c.f;
}
__device__ __forceinline__ float bf2f_hi(u32 u) {
  union { u32 i; float f; } c; c.i = u & 0xffff0000u; return c.f;
}
// packed f32x2 -> bf16x2 (v_cvt_pk_bf16_f32 on gfx950), RNE
__device__ __forceinline__ u32 f2bf2(float a, float b) {
  __hip_bfloat162 h = __float22bfloat162_rn(make_float2(a, b));
  union { __hip_bfloat162 h; u32 u; } c; c.h = h; return c.u;
}
__device__ __forceinline__ u16 f2bf(float f) {
  union { float f; u32 i; } c; c.f = f;
  u32 x = c.i; x += 0x7fffu + ((x >> 16) & 1u);
  return (u16)(x >> 16);
}

// ---- weight convert + transpose: wt[slot][n][k] = W[slot][k][n] as bf16 ----
__global__ void wconv_kernel(const float* __restrict__ Ws, const float* __restrict__ Wq,
                             const float* __restrict__ Wk, const float* __restrict__ Wv,
                             const float* __restrict__ Wo, u16* __restrict__ wt) {
  int idx = blockIdx.x * 256 + threadIdx.x;      // grid sized exactly (9*16384/256)
  int slot = idx >> 14;
  int rem = idx & 16383;
  int n = rem >> 7, k = rem & 127;
  const float* src;
  if (slot == 0) src = Ws;
  else {
    int l = (slot - 1) >> 2, t = (slot - 1) & 3;
    const float* base = (t == 0) ? Wq : (t == 1) ? Wk : (t == 2) ? Wv : Wo;
    src = base + l * (H * H);
  }
  wt[idx] = f2bf(src[k * H + n]);
}

// One projection, B-operand from LDS, A-operand (weights) from global/L2.
// D[outcol=(lane>>4)*4+r][generow=lane&15]: thread owns 1 gene-row x 4 cols per nt.
// unroll 2 caps operand hoisting: peak live ~= 12 acc + 6 B + 2 A + addr (r5's
// full-unroll hoist put 100+ regs live against an 80-reg budget -> 230 MB spill).
__device__ __forceinline__ void proj1(const u16* __restrict__ lds,
                                      const u16* __restrict__ w,
                                      floatx4 acc[3], int m0, int qi, int wrow) {
#pragma unroll
  for (int nt = 0; nt < 3; nt++)
    acc[nt] = (floatx4){0.f, 0.f, 0.f, 0.f};
#pragma unroll 2
  for (int kk = 0; kk < 4; kk++) {
    bf16x8 a = *reinterpret_cast<const bf16x8*>(w + wrow * H + kk * 32 + qi * 8);
    bf16x8 b0 = *reinterpret_cast<const bf16x8*>(lds + (0 * 16 + m0) * BP + kk * 32 + qi * 8);
    bf16x8 b1 = *reinterpret_cast<const bf16x8*>(lds + (1 * 16 + m0) * BP + kk * 32 + qi * 8);
    bf16x8 b2 = *reinterpret_cast<const bf16x8*>(lds + (2 * 16 + m0) * BP + kk * 32 + qi * 8);
    acc[0] = __builtin_amdgcn_mfma_f32_16x16x32_bf16(a, b0, acc[0], 0, 0, 0);
    acc[1] = __builtin_amdgcn_mfma_f32_16x16x32_bf16(a, b1, acc[1], 0, 0, 0);
    acc[2] = __builtin_amdgcn_mfma_f32_16x16x32_bf16(a, b2, acc[2], 0, 0, 0);
  }
}

// store acc+bias as packed bf16, 4 consecutive cols per row -> one b64 write per nt
__device__ __forceinline__ void store_proj(u16* __restrict__ buf, const floatx4 acc[3],
                                           float4 b4, int m0, int colb) {
#pragma unroll
  for (int nt = 0; nt < 3; nt++) {
    uint2 pp;
    pp.x = f2bf2(acc[nt][0] + b4.x, acc[nt][1] + b4.y);
    pp.y = f2bf2(acc[nt][2] + b4.z, acc[nt][3] + b4.w);
    *reinterpret_cast<uint2*>(buf + (nt * 16 + m0) * BP + colb) = pp;
  }
}

__global__ void __launch_bounds__(NT)
__attribute__((amdgpu_waves_per_eu(6)))   // 6 waves/SIMD -> 3 blocks/CU; reg budget 80
dango_kernel(const float* __restrict__ x, const u16* __restrict__ wt,
             const float* __restrict__ bs, const float* __restrict__ bq,
             const float* __restrict__ bk, const float* __restrict__ bv,
             const float* __restrict__ bo, const float* __restrict__ beta,
             const float* __restrict__ Wp, const float* __restrict__ bp,
             float* __restrict__ out)
{
  // ~54 KB LDS -> 3 blocks/CU (3 x 54016 <= 163840)
  __shared__ __align__(16) u16 xbf[MR][BP];   // bf16 residual stream
  __shared__ __align__(16) u16 qbuf[MR][BP];  // Q, then V
  __shared__ __align__(16) u16 kbuf[MR][BP];  // K, then attention-out
  __shared__ __align__(16) u16 statb[MR][BP]; // static embedding
  __shared__ __align__(16) float ovl[MR * 9]; // overlay: attnw (384 f) / rowsc (432 f)
#define ATTNW(g, h, i, p) ovl[((((g) * NHEADS + (h)) * SG + (i)) << 1) + (p)]
#define ROWSC(r, w) ovl[(r) * 9 + (w)]

  const int tid = threadIdx.x;
  const int lane = tid & 63;
  const int wave = tid >> 6;          // 0..7: owns outcols wave*16..wave*16+15
  const int m0 = lane & 15;           // gene-row index within nt-tile
  const int qi = lane >> 4;           // 0..3: 4-col / k-slice window
  const int colb = wave * 16 + qi * 4;
  const int wrow = wave * 16 + m0;    // weight row (outcol) this lane loads
  const int row0 = blockIdx.x * MR;

  float dynf[3][4];                   // final-layer dyn (tail-only live range)
  floatx4 acc[3];

  // ---- init: x -> xbf (bf16 residual) ----
#pragma unroll
  for (int nt = 0; nt < 3; nt++) {
    int row = nt * 16 + m0;
    float4 v = *reinterpret_cast<const float4*>(x + (size_t)(row0 + row) * H + colb);
    uint2 pp; pp.x = f2bf2(v.x, v.y); pp.y = f2bf2(v.z, v.w);
    *reinterpret_cast<uint2*>(&xbf[row][colb]) = pp;
  }
  __syncthreads();

  // ---- phase A: static -> statb, Q -> qbuf, K -> kbuf (all read xbf) ----
  proj1(&xbf[0][0], wt, acc, m0, qi, wrow);
  {
    float4 b4 = *reinterpret_cast<const float4*>(bs + colb);
#pragma unroll
    for (int nt = 0; nt < 3; nt++) {
      uint2 pp;
      pp.x = f2bf2(fmaxf(acc[nt][0] + b4.x, 0.f), fmaxf(acc[nt][1] + b4.y, 0.f));
      pp.y = f2bf2(fmaxf(acc[nt][2] + b4.z, 0.f), fmaxf(acc[nt][3] + b4.w, 0.f));
      *reinterpret_cast<uint2*>(&statb[nt * 16 + m0][colb]) = pp;
    }
  }
  proj1(&xbf[0][0], wt + (size_t)1 * H * H, acc, m0, qi, wrow);
  store_proj(&qbuf[0][0], acc, *reinterpret_cast<const float4*>(bq + colb), m0, colb);
  proj1(&xbf[0][0], wt + (size_t)2 * H * H, acc, m0, qi, wrow);
  store_proj(&kbuf[0][0], acc, *reinterpret_cast<const float4*>(bk + colb), m0, colb);
  __syncthreads();

  for (int l = 0; l < NLAYERS; l++) {
    // ---- scores + 2-way softmax (self excluded): qbuf(Q), kbuf(K) -> attnw ----
    if (tid < GB * NHEADS * SG) {
      int g = tid / (NHEADS * SG);
      int rem = tid % (NHEADS * SG);
      int h = rem / SG;
      int i = rem % SG;
      int j0 = (i == 0) ? 1 : 0;
      int j1 = (i == 2) ? 1 : 2;
      const uint4* qp  = reinterpret_cast<const uint4*>(&qbuf[g * 3 + i][h * HD]);
      const uint4* k0p = reinterpret_cast<const uint4*>(&kbuf[g * 3 + j0][h * HD]);
      const uint4* k1p = reinterpret_cast<const uint4*>(&kbuf[g * 3 + j1][h * HD]);
      float s0 = 0.f, s1 = 0.f;
#pragma unroll
      for (int c = 0; c < 4; c++) {
        uint4 qu = qp[c], u0 = k0p[c], u1 = k1p[c];
        u32 qs[4] = {qu.x, qu.y, qu.z, qu.w};
        u32 a0[4] = {u0.x, u0.y, u0.z, u0.w};
        u32 a1[4] = {u1.x, u1.y, u1.z, u1.w};
#pragma unroll
        for (int e = 0; e < 4; e++) {
          float ql = bf2f_lo(qs[e]), qh = bf2f_hi(qs[e]);
          s0 += ql * bf2f_lo(a0[e]) + qh * bf2f_hi(a0[e]);
          s1 += ql * bf2f_lo(a1[e]) + qh * bf2f_hi(a1[e]);
        }
      }
      s0 *= 0.17677669529663687f;   // 1/sqrt(32)
      s1 *= 0.17677669529663687f;
      float mx = fmaxf(s0, s1);
      float e0 = __expf(s0 - mx), e1 = __expf(s1 - mx);
      float inv = 1.f / (e0 + e1);
      ATTNW(g, h, i, 0) = e0 * inv;
      ATTNW(g, h, i, 1) = e1 * inv;
    }
    __syncthreads();   // Q,K reads done; attnw visible

    // ---- V projection (slot 1+4l+2) -> qbuf (Q dead) ----
    proj1(&xbf[0][0], wt + (size_t)(1 + l * 4 + 2) * H * H, acc, m0, qi, wrow);
    store_proj(&qbuf[0][0], acc, *reinterpret_cast<const float4*>(bv + l * H + colb), m0, colb);
    __syncthreads();   // V visible

    // ---- attention-out = attn @ V : qbuf(V) -> kbuf (K dead) ----
    for (int ch = tid; ch < MR * 16; ch += NT) {
      int r = ch >> 4, c0 = (ch & 15) << 3;
      int g = r / 3, i = r - g * 3, h = c0 >> 5;
      int j0 = (i == 0) ? 1 : 0;
      int j1 = (i == 2) ? 1 : 2;
      float a0 = ATTNW(g, h, i, 0), a1 = ATTNW(g, h, i, 1);
      uint4 v0 = *reinterpret_cast<const uint4*>(&qbuf[g * 3 + j0][c0]);
      uint4 v1 = *reinterpret_cast<const uint4*>(&qbuf[g * 3 + j1][c0]);
      u32 w0[4] = {v0.x, v0.y, v0.z, v0.w};
      u32 w1[4] = {v1.x, v1.y, v1.z, v1.w};
      u32 oo[4];
#pragma unroll
      for (int e = 0; e < 4; e++) {
        float lo = a0 * bf2f_lo(w0[e]) + a1 * bf2f_lo(w1[e]);
        float hi = a0 * bf2f_hi(w0[e]) + a1 * bf2f_hi(w1[e]);
        oo[e] = f2bf2(lo, hi);
      }
      uint4 o; o.x = oo[0]; o.y = oo[1]; o.z = oo[2]; o.w = oo[3];
      *reinterpret_cast<uint4*>(&kbuf[r][c0]) = o;
    }
    __syncthreads();   // attn-out visible

    // ---- O-projection (slot 1+4l+3) + ReZero RMW on xbf (own cells) ----
    proj1(&kbuf[0][0], wt + (size_t)(1 + l * 4 + 3) * H * H, acc, m0, qi, wrow);
    {
      float4 b4 = *reinterpret_cast<const float4*>(bo + l * H + colb);
      const float betal = beta[l];
#pragma unroll
      for (int nt = 0; nt < 3; nt++) {
        int row = nt * 16 + m0;
        uint2 pp = *reinterpret_cast<const uint2*>(&xbf[row][colb]);
        float r0 = bf2f_lo(pp.x) + betal * (acc[nt][0] + b4.x);
        float r1 = bf2f_hi(pp.x) + betal * (acc[nt][1] + b4.y);
        float r2 = bf2f_lo(pp.y) + betal * (acc[nt][2] + b4.z);
        float r3 = bf2f_hi(pp.y) + betal * (acc[nt][3] + b4.w);
        if (l + 1 < NLAYERS) {
          uint2 np; np.x = f2bf2(r0, r1); np.y = f2bf2(r2, r3);
          *reinterpret_cast<uint2*>(&xbf[row][colb]) = np;
        } else {
          dynf[nt][0] = r0; dynf[nt][1] = r1; dynf[nt][2] = r2; dynf[nt][3] = r3;
        }
      }
    }

    if (l + 1 < NLAYERS) {
      __syncthreads();   // new residual visible
      // ---- Q,K of layer l+1 ----
      proj1(&xbf[0][0], wt + (size_t)(1 + (l + 1) * 4 + 0) * H * H, acc, m0, qi, wrow);
      store_proj(&qbuf[0][0], acc, *reinterpret_cast<const float4*>(bq + (l + 1) * H + colb), m0, colb);
      proj1(&xbf[0][0], wt + (size_t)(1 + (l + 1) * 4 + 1) * H * H, acc, m0, qi, wrow);
      store_proj(&kbuf[0][0], acc, *reinterpret_cast<const float4*>(bk + (l + 1) * H + colb), m0, colb);
      __syncthreads();
    }
  }

  // ---- readout: gene score = sum_c (dyn-stat)^2 * Wp[c]; group mean ----
  float4 wp4 = *reinterpret_cast<const float4*>(Wp + colb);
  float rsum[3];
#pragma unroll
  for (int nt = 0; nt < 3; nt++) {
    uint2 sp = *reinterpret_cast<const uint2*>(&statb[nt * 16 + m0][colb]);
    float d0 = dynf[nt][0] - bf2f_lo(sp.x);
    float d1 = dynf[nt][1] - bf2f_hi(sp.x);
    float d2 = dynf[nt][2] - bf2f_lo(sp.y);
    float d3 = dynf[nt][3] - bf2f_hi(sp.y);
    rsum[nt] = d0 * d0 * wp4.x + d1 * d1 * wp4.y + d2 * d2 * wp4.z + d3 * d3 * wp4.w;
  }
  // reduce over qi (lane bits 4,5): each row's 16 cols within this wave
#pragma unroll
  for (int nt = 0; nt < 3; nt++) {
    rsum[nt] += __shfl_xor(rsum[nt], 16, 64);
    rsum[nt] += __shfl_xor(rsum[nt], 32, 64);
  }
  if (qi == 0) {
#pragma unroll
    for (int nt = 0; nt < 3; nt++)
      ROWSC(nt * 16 + m0, wave) = rsum[nt];
  }
  __syncthreads();
  if (tid < GB) {
    float s = 0.f;
#pragma unroll
    for (int i = 0; i < SG; i++) {
      int row = tid * 3 + i;
#pragma unroll
      for (int w = 0; w < 8; w++) s += ROWSC(row, w);
    }
    out[blockIdx.x * GB + tid] = s * (1.f / 3.f) + bp[0];
  }
}

extern "C" void kernel_launch(void* const* d_in, const int* in_sizes, int n_in,
                              void* d_out, int out_size, void* d_ws, size_t ws_size,
                              hipStream_t stream) {
  const float* x    = (const float*)d_in[0];
  // d_in[1] = batch ids: deterministic repeat(arange(G),3) -> not needed
  const float* Ws   = (const float*)d_in[2];
  const float* bs   = (const float*)d_in[3];
  const float* Wq   = (const float*)d_in[4];
  const float* bq   = (const float*)d_in[5];
  const float* Wk   = (const float*)d_in[6];
  const float* bk   = (const float*)d_in[7];
  const float* Wv   = (const float*)d_in[8];
  const float* bv   = (const float*)d_in[9];
  const float* Wo   = (const float*)d_in[10];
  const float* bo   = (const float*)d_in[11];
  const float* beta = (const float*)d_in[12];
  const float* Wp   = (const float*)d_in[13];
  const float* bp   = (const float*)d_in[14];
  float* out = (float*)d_out;
  u16* wt = (u16*)d_ws;   // 9 * 128*128 bf16 = 294,912 B

  // ws is re-poisoned before every launch -> convert every call
  wconv_kernel<<<576, 256, 0, stream>>>(Ws, Wq, Wk, Wv, Wo, wt);
  dango_kernel<<<NGROUPS / GB, NT, 0, stream>>>(x, wt, bs, bq, bk, bv, bo, beta, Wp, bp, out);
}